// Round 6
// baseline (826.971 us; speedup 1.0000x reference)
//
#include <hip/hip_runtime.h>
#include <math.h>

#define BB 8192
#define TT 60
#define NU 100
#define NI 7

typedef float v2f __attribute__((ext_vector_type(2)));
typedef float v4f __attribute__((ext_vector_type(4)));

// R6 structure: block = 128 threads = 2 waves = ONE trial.
//   wave0 accumulates k in [0,50), wave1 k in [50,100) -> 50 v2f weights/lane
//   (100 VGPRs), under the allocator's demonstrated ~124-arch ceiling, so no
//   AGPR shuttle (R2-R5's hidden ~340 instr/step) and no scratch spill (R5).
// Both waves hold full y (lane l -> units 2l,2l+1), run bit-identical update
// and control logic; only MAC partials are exchanged (LDS + 1 barrier/step).
// y broadcast = own-wave LDS strip, written rotated so BOTH waves read bytes
// [0,200) as 12 x ds_read_b128 + 1 x ds_read_b64 (uniform addr = broadcast).

#define FOR50(M) M(0) M(1) M(2) M(3) M(4) M(5) M(6) M(7) M(8) M(9) \
  M(10) M(11) M(12) M(13) M(14) M(15) M(16) M(17) M(18) M(19) \
  M(20) M(21) M(22) M(23) M(24) M(25) M(26) M(27) M(28) M(29) \
  M(30) M(31) M(32) M(33) M(34) M(35) M(36) M(37) M(38) M(39) \
  M(40) M(41) M(42) M(43) M(44) M(45) M(46) M(47) M(48) M(49)

// w_j = {W_rec[2l][kbase+j], W_rec[2l+1][kbase+j]}  (j = k-local)
#define DECLW(j) const v2f w_##j = { W_rec[uaoff + kbase + (j)], W_rec[uboff + kbase + (j)] };

#define RL(v,l) __int_as_float(__builtin_amdgcn_readlane(__float_as_int(v), l))

// quad MAC: 4 broadcast y values (k-local 4q..4q+3) x pk_fma into 2 chains
#define MACQ(q, wa, wb, wc, wd) { \
  const v4f yq = *(const v4f*)(yb + 16*(q)); \
  acc0 += wa * (v2f){yq.x, yq.x}; \
  acc1 += wb * (v2f){yq.y, yq.y}; \
  acc0 += wc * (v2f){yq.z, yq.z}; \
  acc1 += wd * (v2f){yq.w, yq.w}; }

#define DPPADD(ctrl, rmask) { \
  const int _t = __builtin_amdgcn_update_dpp(0, __float_as_int(part), (ctrl), (rmask), 0xf, false); \
  part += __int_as_float(_t); }

__global__ __launch_bounds__(128, 4)
void drr_kernel(const float* __restrict__ y0,
                const float* __restrict__ noise,
                const int*   __restrict__ stim_idx,
                const int*   __restrict__ rew_idx,
                const int*   __restrict__ instr_in,
                const float* __restrict__ W_in_raw,
                const float* __restrict__ W_rec,
                const float* __restrict__ b_rec,
                const float* __restrict__ w_out,
                const float* __restrict__ b_out,
                float* __restrict__ out)
{
    __shared__ __align__(16) float ybc[2][128];  // per-wave y broadcast strip
    __shared__ v2f pex[2][2][64];                // [parity][wave][lane] partials

    const int lane  = threadIdx.x & 63;
    const int wid   = (threadIdx.x >> 6) & 1;    // 0: k<50, 1: k>=50
    const int trial = blockIdx.x;

    const bool act = (lane < 50);
    const int  la  = act ? lane : 49;            // clamped (lanes>=50 mirror 49)
    const int  ua  = 2 * la;
    const int  uaoff = ua * NU;
    const int  uboff = uaoff + NU;
    const int  kbase = wid * 50;

    // per-trial scalars (wave-uniform -> SGPRs)
    const int  stim    = stim_idx[trial];
    const int  rew     = rew_idx[trial];
    const bool is_rew  = (stim == rew);
    const bool instr_b = (instr_in[trial] > 0);

    // 50 v2f weight registers (100 VGPRs)
    FOR50(DECLW)

    // input-weight columns (abs), packed per unit pair
    const v2f wi6 = { fabsf(W_in_raw[ua * NI + 6]),    fabsf(W_in_raw[(ua+1) * NI + 6]) };
    const v2f wis = { fabsf(W_in_raw[ua * NI + stim]), fabsf(W_in_raw[(ua+1) * NI + stim]) };
    const v2f wr  = { fabsf(W_in_raw[ua * NI + 4]),    fabsf(W_in_raw[(ua+1) * NI + 4]) };
    const v2f wl  = { fabsf(W_in_raw[ua * NI + 5]),    fabsf(W_in_raw[(ua+1) * NI + 5]) };
    const v2f br  = { b_rec[ua], b_rec[ua + 1] };
    const v2f wo  = act ? (v2f){ w_out[ua], w_out[ua + 1] } : (v2f){ 0.0f, 0.0f };
    const float bo = b_out[0];

    v2f yy = *(const v2f*)(y0 + trial * NU + ua);

    const float NS = 0.09486832980505138f; // 0.15 * sqrt(2*0.2)

    // control state — wave-uniform, identical in both waves
    bool licked = false, instr_fired = false;
    int  lick_t = TT + 1;

    const float* np = noise + trial * (TT * NU) + ua;
    v2f en = *(const v2f*)np;                    // t=0 prefetch

    // y-broadcast strip addressing: write unit u at slot (u - kbase) mod 100
    // so BOTH waves read k-local j at float j (bytes [0,200)).
    char* ybw = (char*)&ybc[wid][0] + (((ua + (wid ? 50 : 0)) % 100) * 4);
    const char* yb = (const char*)&ybc[wid][0];

    // output section pointers (flat tuple order)
    float* uout  = out;                        // B*T*7
    float* tout  = out  + BB * TT * NI;        // B*T
    float* rout  = tout + BB * TT;             // B*T
    float* lout  = rout + BB * TT;             // B
    float* dout  = lout + BB;                  // B
    float* zout  = dout + BB;                  // B*T
    float* yfout = zout + BB * TT;             // B*100

    for (int t = 0; t < TT; ++t) {
        // publish current y to own broadcast strip (within-wave RAW, no barrier)
        *(v2f*)ybw = yy;

        const v2f e = en;
        if (t < TT - 1)
            en = *(const v2f*)(np + (t + 1) * NU);

        // reward routing (state from previous step), wave-uniform
        const bool delivered    = instr_fired || (licked && is_rew);
        const bool fire         = instr_b && !delivered && (t == 30);
        instr_fired             = instr_fired || fire;
        const bool instr_active = instr_fired && (t >= 30) && (t < 35);
        const bool lick_dyn     = licked && (t > lick_t) && (t < lick_t + 5);
        const float a_rew  = (instr_active ? 1.0f : 0.0f) + ((lick_dyn && is_rew) ? 1.0f : 0.0f);
        const float a_lick = lick_dyn ? 1.0f : 0.0f;

        const bool in_stim = (t >= 10) && (t < 15);
        const bool in_resp = (t >= 20) && (t < 35);

        // ---- 50-deep MAC over own k-half (broadcast y from LDS) ----
        v2f acc0 = { 0.0f, 0.0f };
        v2f acc1 = { 0.0f, 0.0f };
        MACQ(0,  w_0,  w_1,  w_2,  w_3)
        MACQ(1,  w_4,  w_5,  w_6,  w_7)
        MACQ(2,  w_8,  w_9,  w_10, w_11)
        MACQ(3,  w_12, w_13, w_14, w_15)
        MACQ(4,  w_16, w_17, w_18, w_19)
        MACQ(5,  w_20, w_21, w_22, w_23)
        MACQ(6,  w_24, w_25, w_26, w_27)
        MACQ(7,  w_28, w_29, w_30, w_31)
        MACQ(8,  w_32, w_33, w_34, w_35)
        MACQ(9,  w_36, w_37, w_38, w_39)
        MACQ(10, w_40, w_41, w_42, w_43)
        MACQ(11, w_44, w_45, w_46, w_47)
        { const v2f yp = *(const v2f*)(yb + 192);
          acc0 += w_48 * (v2f){yp.x, yp.x};
          acc1 += w_49 * (v2f){yp.y, yp.y}; }

        // ---- exchange partials (parity double-buffer, 1 barrier/step) ----
        const int par = t & 1;
        const v2f pown = acc0 + acc1;
        pex[par][wid][lane] = pown;
        __syncthreads();
        const v2f pothr = pex[par][wid ^ 1][lane];
        const v2f plo = wid ? pothr : pown;   // k<50 partial
        const v2f phi = wid ? pown  : pothr;  // k>=50 partial

        // ---- base terms (identical in both waves) ----
        v2f base = br;
        if (in_stim) base += wis;
        if (in_resp) base += wi6;
        if (a_rew  != 0.0f) base += (v2f){a_rew, a_rew} * wr;
        if (a_lick != 0.0f) base += (v2f){a_lick, a_lick} * wl;
        base += (v2f){NS, NS} * e;

        v2f pre = base + (plo + phi);
        pre = (v2f){ fmaxf(pre.x, 0.0f), fmaxf(pre.y, 0.0f) };
        yy = (v2f){0.8f, 0.8f} * yy + (v2f){0.2f, 0.2f} * pre;

        // ---- z = sigmoid(y . w_out + b_out), DPP wave64 reduction ----
        float part = yy.x * wo.x + yy.y * wo.y;
        DPPADD(0x111, 0xf)   // row_shr:1
        DPPADD(0x112, 0xf)   // row_shr:2
        DPPADD(0x114, 0xf)   // row_shr:4
        DPPADD(0x118, 0xf)   // row_shr:8
        DPPADD(0x142, 0xa)   // row_bcast:15 -> rows 1,3
        DPPADD(0x143, 0xc)   // row_bcast:31 -> rows 2,3
        const float x = RL(part, 63) + bo;
        const float z = 1.0f / (1.0f + expf(-x));

        const bool trig = in_resp && !licked && (z > 0.5f);
        if (trig) lick_t = t;
        licked = licked || trig;
        const bool u5 = licked && (t >= lick_t) && (t < lick_t + 5);
        const bool u4 = instr_active || (u5 && is_rew);

        const float sm = in_stim ? 1.0f : 0.0f;
        const float rm = in_resp ? 1.0f : 0.0f;

        // ---- per-step outputs (wave0 only) ----
        if (!wid) {
            const int bt = trial * TT + t;
            if (lane < NI) {
                float uv = 0.0f;
                if (lane == stim) uv = sm;                 // stim in [0,4)
                if (lane == 4)    uv = u4 ? 1.0f : 0.0f;
                if (lane == 5)    uv = u5 ? 1.0f : 0.0f;
                if (lane == 6)    uv = rm;
                uout[bt * NI + lane] = uv;
            } else if (lane == 8) {
                tout[bt] = is_rew ? rm : 0.0f;
            } else if (lane == 9) {
                rout[bt] = rm;
            } else if (lane == 10) {
                zout[bt] = z;
            }
        }
    }

    if (!wid) {
        if (lane == 0) {
            lout[trial] = licked ? 1.0f : 0.0f;
            dout[trial] = (instr_fired || (licked && is_rew)) ? 1.0f : 0.0f;
        }
        if (act)
            *(v2f*)(yfout + trial * NU + ua) = yy;
    }
}

extern "C" void kernel_launch(void* const* d_in, const int* in_sizes, int n_in,
                              void* d_out, int out_size, void* d_ws, size_t ws_size,
                              hipStream_t stream) {
    const float* y0       = (const float*)d_in[0];
    const float* noise    = (const float*)d_in[1];
    const int*   stim     = (const int*)  d_in[2];
    const int*   rew      = (const int*)  d_in[3];
    const int*   instr    = (const int*)  d_in[4];
    const float* W_in_raw = (const float*)d_in[5];
    const float* W_rec    = (const float*)d_in[6];
    const float* b_rec    = (const float*)d_in[7];
    const float* w_out    = (const float*)d_in[8];
    const float* b_out    = (const float*)d_in[9];
    float* out = (float*)d_out;

    // one trial per 128-thread block (2 waves, k split 50/50)
    drr_kernel<<<BB, 128, 0, stream>>>(y0, noise, stim, rew, instr,
                                       W_in_raw, W_rec, b_rec, w_out, b_out, out);
}